// Round 3
// baseline (638.104 us; speedup 1.0000x reference)
//
#include <hip/hip_runtime.h>
#include <stdint.h>

#define HH 64
#define WW 64
#define AA 9
#define N_PER (HH*WW*AA)   // 36864
#define NSORT 65536
#define NB 4
#define PRE_NMS 6000
#define POST_NMS 300
#define NMS_THRESH 0.7f
#define FEAT_STRIDE 16
#define TILE 2048

// ---------------- Phase 1: decode boxes + build sort keys ----------------
__global__ void proposal_kernel(const float* __restrict__ scores,
                                const float* __restrict__ deltas,
                                const float* __restrict__ img_info,
                                const float* __restrict__ anchors,
                                float* __restrict__ props,       // NB*N_PER*4
                                uint64_t* __restrict__ keys)     // NB*NSORT
{
#pragma clang fp contract(off)
    int tid = blockIdx.x * blockDim.x + threadIdx.x;
    int b = tid >> 16;
    int i = tid & 65535;
    if (b >= NB) return;
    if (i >= N_PER) { keys[(size_t)b*NSORT + i] = 0ull; return; }
    int a = i % AA;
    int s = i / AA;
    int w = s % WW;
    int h = s / WW;
    float sx = (float)(w * FEAT_STRIDE);
    float sy = (float)(h * FEAT_STRIDE);
    float ax1 = anchors[a*4+0] + sx;
    float ay1 = anchors[a*4+1] + sy;
    float ax2 = anchors[a*4+2] + sx;
    float ay2 = anchors[a*4+3] + sy;
    float width  = ax2 - ax1 + 1.0f;
    float height = ay2 - ay1 + 1.0f;
    float cx = ax1 + 0.5f * width;
    float cy = ay1 + 0.5f * height;
    size_t base = ((size_t)b*36 + a*4) * (HH*WW) + (size_t)h*WW + w;
    float dx = deltas[base];
    float dy = deltas[base + HH*WW];
    float dw = deltas[base + 2*HH*WW];
    float dh = deltas[base + 3*HH*WW];
    float pcx = dx * width + cx;
    float pcy = dy * height + cy;
    float pw = (float)exp((double)dw) * width;   // correctly-rounded f32 exp
    float ph = (float)exp((double)dh) * height;
    float x1 = pcx - 0.5f * pw;
    float y1 = pcy - 0.5f * ph;
    float x2 = pcx + 0.5f * pw;
    float y2 = pcy + 0.5f * ph;
    float maxx = img_info[1] - 1.0f;
    float maxy = img_info[0] - 1.0f;
    x1 = fminf(fmaxf(x1, 0.0f), maxx);
    y1 = fminf(fmaxf(y1, 0.0f), maxy);
    x2 = fminf(fmaxf(x2, 0.0f), maxx);
    y2 = fminf(fmaxf(y2, 0.0f), maxy);
    float4* pp = (float4*)(props + ((size_t)b*N_PER + i)*4);
    *pp = make_float4(x1, y1, x2, y2);
    float sc = scores[((size_t)b*18 + 9 + a) * (HH*WW) + (size_t)h*WW + w];
    uint32_t u = __float_as_uint(sc);
    u = (u & 0x80000000u) ? ~u : (u | 0x80000000u);   // monotonic float->uint
    uint64_t key = ((uint64_t)u << 32) | (uint32_t)(~(uint32_t)i);
    keys[(size_t)b*NSORT + i] = key;
}

// ---------------- Phase 2: bitonic sort (descending) ----------------
__global__ void __launch_bounds__(1024) bitonic_local_sort(uint64_t* keys) {
    __shared__ uint64_t sk[TILE];
    int tile = blockIdx.x;
    uint64_t* base = keys + (size_t)tile * TILE;
    int lt = threadIdx.x;
    sk[lt] = base[lt];
    sk[lt + 1024] = base[lt + 1024];
    __syncthreads();
    int gbase = (tile & (NSORT/TILE - 1)) * TILE;   // per-image element offset
    for (int size = 2; size <= TILE; size <<= 1) {
        for (int stride = size >> 1; stride > 0; stride >>= 1) {
            int idx = ((lt & ~(stride-1)) << 1) | (lt & (stride-1));
            int partner = idx | stride;
            int gi = gbase + idx;
            bool up = (gi & size) == 0;  // descending overall
            uint64_t x = sk[idx], y = sk[partner];
            if (up ? (x < y) : (x > y)) { sk[idx] = y; sk[partner] = x; }
            __syncthreads();
        }
    }
    base[lt] = sk[lt];
    base[lt + 1024] = sk[lt + 1024];
}

__global__ void bitonic_global_pass(uint64_t* keys, int size, int stride) {
    int tid = blockIdx.x * blockDim.x + threadIdx.x;  // NB*NSORT/2 pairs
    int img = tid >> 15;
    int p = tid & 32767;
    int idx = ((p & ~(stride-1)) << 1) | (p & (stride-1));
    int partner = idx | stride;
    bool up = (idx & size) == 0;
    uint64_t* base = keys + (size_t)img * NSORT;
    uint64_t x = base[idx], y = base[partner];
    if (up ? (x < y) : (x > y)) { base[idx] = y; base[partner] = x; }
}

__global__ void __launch_bounds__(1024) bitonic_local_tail(uint64_t* keys, int size) {
    __shared__ uint64_t sk[TILE];
    int tile = blockIdx.x;
    uint64_t* base = keys + (size_t)tile * TILE;
    int lt = threadIdx.x;
    sk[lt] = base[lt]; sk[lt+1024] = base[lt+1024];
    __syncthreads();
    int gbase = (tile & (NSORT/TILE - 1)) * TILE;
    bool up = ((gbase & size) == 0);  // uniform per tile (size > TILE)
    for (int stride = TILE/2; stride > 0; stride >>= 1) {
        int idx = ((lt & ~(stride-1)) << 1) | (lt & (stride-1));
        int partner = idx | stride;
        uint64_t x = sk[idx], y = sk[partner];
        if (up ? (x < y) : (x > y)) { sk[idx] = y; sk[partner] = x; }
        __syncthreads();
    }
    base[lt] = sk[lt]; base[lt+1024] = sk[lt+1024];
}

// ---------------- Phase 3: fused gather + greedy NMS + output ----------------
// One block of 1024 threads per image. Boxes of the top-6000 ranks live in LDS;
// each thread owns 6 consecutive ranks in registers. Per kept candidate:
// LDS broadcast of candidate box, 6 register IoUs, clear alive bits, block-wide
// min-reduce (shfl + double-buffered LDS slots -> ONE barrier per iteration).
__global__ void __launch_bounds__(1024) nms_fused(const uint64_t* __restrict__ keys,
                                                  const float* __restrict__ props,
                                                  float* __restrict__ out)
{
#pragma clang fp contract(off)
    int b = blockIdx.x;
    int t = threadIdx.x;
    __shared__ float4 boxes[PRE_NMS];     // 96,000 B
    __shared__ int wavemin[2][16];
    __shared__ int keepLds[POST_NMS];

    float bx1[6], by1[6], bx2[6], by2[6], areas[6];
    uint32_t alive = 0u;
    #pragma unroll
    for (int k = 0; k < 6; ++k) {
        int r = t*6 + k;
        float4 box = make_float4(0.f, 0.f, 0.f, 0.f);
        if (r < PRE_NMS) {
            uint64_t key = keys[(size_t)b*NSORT + r];
            uint32_t idx = ~(uint32_t)(key & 0xFFFFFFFFu);
            box = *(const float4*)(props + ((size_t)b*N_PER + idx)*4);
            boxes[r] = box;
            alive |= (1u << k);
        }
        bx1[k] = box.x; by1[k] = box.y; bx2[k] = box.z; by2[k] = box.w;
        areas[k] = (box.z - box.x + 1.0f) * (box.w - box.y + 1.0f);
    }
    __syncthreads();

    int nkeep = 0;
    int cand = 0;     // rank 0 is never suppressed initially
    int par = 0;
    while (true) {
        if (t == 0) keepLds[nkeep] = cand;
        nkeep++;
        if (nkeep >= POST_NMS) break;

        float4 bi = boxes[cand];                 // uniform LDS broadcast
        float wi = bi.z - bi.x + 1.0f;
        float hi_ = bi.w - bi.y + 1.0f;
        float areai = wi * hi_;
        #pragma unroll
        for (int k = 0; k < 6; ++k) {
            float xx1 = fmaxf(bi.x, bx1[k]);
            float yy1 = fmaxf(bi.y, by1[k]);
            float xx2 = fminf(bi.z, bx2[k]);
            float yy2 = fminf(bi.w, by2[k]);
            float iw = fmaxf(0.0f, xx2 - xx1 + 1.0f);
            float ih = fmaxf(0.0f, yy2 - yy1 + 1.0f);
            float inter = iw * ih;
            float iou = inter / ((areai + areas[k]) - inter);
            if (iou > NMS_THRESH) alive &= ~(1u << k);
        }
        // self-IoU (==1.0) cleared cand's own bit, so min alive is strictly > cand
        int local = alive ? (t*6 + (__ffs(alive) - 1)) : 0x7FFFFFFF;
        #pragma unroll
        for (int off = 32; off >= 1; off >>= 1)
            local = min(local, __shfl_xor(local, off));
        if ((t & 63) == 0) wavemin[par][t >> 6] = local;
        __syncthreads();
        const int4* wm = (const int4*)wavemin[par];
        int4 a0 = wm[0], a1 = wm[1], a2 = wm[2], a3 = wm[3];
        int m = min(min(min(a0.x, a0.y), min(a0.z, a0.w)),
                min(min(min(a1.x, a1.y), min(a1.z, a1.w)),
                min(min(min(a2.x, a2.y), min(a2.z, a2.w)),
                    min(min(a3.x, a3.y), min(a3.z, a3.w)))));
        par ^= 1;   // double-buffer: next iter writes other slot, no 2nd barrier
        if (m == 0x7FFFFFFF) break;
        cand = m;
    }
    __syncthreads();   // keepLds visible to all

    if (t < POST_NMS) {
        float* o = out + ((size_t)b*POST_NMS + t)*5;
        o[0] = (float)b;
        if (t < nkeep) {
            float4 bx = boxes[keepLds[t]];
            o[1] = bx.x; o[2] = bx.y; o[3] = bx.z; o[4] = bx.w;
        } else {
            o[1] = 0.0f; o[2] = 0.0f; o[3] = 0.0f; o[4] = 0.0f;
        }
    }
}

extern "C" void kernel_launch(void* const* d_in, const int* in_sizes, int n_in,
                              void* d_out, int out_size, void* d_ws, size_t ws_size,
                              hipStream_t stream) {
    const float* scores   = (const float*)d_in[0];
    const float* deltas   = (const float*)d_in[1];
    const float* img_info = (const float*)d_in[2];
    const float* anchors  = (const float*)d_in[3];
    float* out = (float*)d_out;

    uint8_t* ws = (uint8_t*)d_ws;
    float*    props = (float*)ws;                 // 2,359,296 B
    uint64_t* keys  = (uint64_t*)(ws + 2359296);  // 2,097,152 B

    proposal_kernel<<<(NB*NSORT)/256, 256, 0, stream>>>(scores, deltas, img_info, anchors, props, keys);

    bitonic_local_sort<<<NB*NSORT/TILE, 1024, 0, stream>>>(keys);
    for (int size = 4096; size <= NSORT; size <<= 1) {
        for (int stride = size >> 1; stride >= TILE; stride >>= 1)
            bitonic_global_pass<<<(NB*NSORT/2)/256, 256, 0, stream>>>(keys, size, stride);
        bitonic_local_tail<<<NB*NSORT/TILE, 1024, 0, stream>>>(keys, size);
    }

    nms_fused<<<NB, 1024, 0, stream>>>(keys, props, out);
}

// Round 4
// 437.687 us; speedup vs baseline: 1.4579x; 1.4579x over previous
//
#include <hip/hip_runtime.h>
#include <stdint.h>

#define HH 64
#define WW 64
#define AA 9
#define N_PER (HH*WW*AA)   // 36864
#define NB 4
#define PRE_NMS 6000
#define POST_NMS 300
#define JWORDS 94          // ceil(6000/64); row = 752 B = 47 lanes * 16 B
#define NMS_THRESH 0.7f
#define FEAT_STRIDE 16

// =====================================================================
// Kernel 1: exact top-6000 select (radix on unique 64-bit composite keys)
// + LDS bitonic sort + box decode of the selected 6000. One WG per image.
// Composite key = (monotonic(score) << 32) | ~index  -> unique, and
// descending order == jax.lax.top_k order (ties -> lower index first).
// =====================================================================
__global__ void __launch_bounds__(1024) select_sort(const float* __restrict__ scores,
                                                    const float* __restrict__ deltas,
                                                    const float* __restrict__ img_info,
                                                    const float* __restrict__ anchors,
                                                    float* __restrict__ topb) // NB*PRE_NMS*4
{
#pragma clang fp contract(off)
    int b = blockIdx.x;
    int t = threadIdx.x;
    __shared__ uint32_t H[2048];
    __shared__ uint32_t S[2048];
    __shared__ uint64_t coll[1024];
    __shared__ uint64_t sortbuf[8192];
    __shared__ uint32_t ccnt, gcnt;
    __shared__ int shB1, shB2;
    __shared__ uint64_t shKstar;

    // --- key for linear element j = a*4096 + hw  (coalesced over hw) ---
    auto keyof = [&](int j) -> uint64_t {
        int a = j >> 12, hw = j & 4095;
        float sc = scores[((size_t)b*18 + 9 + a)*4096 + hw];
        uint32_t u = __float_as_uint(sc);
        u = (u & 0x80000000u) ? ~u : (u | 0x80000000u);
        uint32_t i = (uint32_t)(hw*9 + a);            // reference flat index
        return ((uint64_t)u << 32) | (uint32_t)(~i);
    };

    // ---------- pass 1: histogram of top 11 bits ----------
    H[t] = 0; H[t+1024] = 0;
    __syncthreads();
    for (int j = t; j < N_PER; j += 1024)
        atomicAdd(&H[(uint32_t)(keyof(j) >> 53)], 1u);
    __syncthreads();
    S[t] = H[t]; S[t+1024] = H[t+1024];
    __syncthreads();
    for (int off = 1; off < 2048; off <<= 1) {
        uint32_t v0 = S[t]      + ((t+off)      < 2048 ? S[t+off]      : 0);
        uint32_t v1 = S[t+1024] + ((t+1024+off) < 2048 ? S[t+1024+off] : 0);
        __syncthreads();
        S[t] = v0; S[t+1024] = v1;
        __syncthreads();
    }
    // find B1: S[B1] >= 6000 > S[B1+1]
    for (int k = 0; k < 2; ++k) {
        int bin = t + k*1024;
        uint32_t above = (bin < 2047) ? S[bin+1] : 0;
        if (S[bin] >= PRE_NMS && above < PRE_NMS) shB1 = bin;
    }
    __syncthreads();
    int B1 = shB1;
    uint32_t C1 = (B1 < 2047) ? S[B1+1] : 0;
    uint32_t R1 = PRE_NMS - C1;                       // rank needed within bin B1 (>=1)
    __syncthreads();

    // ---------- pass 2: histogram of next 11 bits within bin B1 ----------
    H[t] = 0; H[t+1024] = 0;
    __syncthreads();
    for (int j = t; j < N_PER; j += 1024) {
        uint64_t k64 = keyof(j);
        if ((int)(k64 >> 53) == B1)
            atomicAdd(&H[(uint32_t)((k64 >> 42) & 2047)], 1u);
    }
    __syncthreads();
    S[t] = H[t]; S[t+1024] = H[t+1024];
    __syncthreads();
    for (int off = 1; off < 2048; off <<= 1) {
        uint32_t v0 = S[t]      + ((t+off)      < 2048 ? S[t+off]      : 0);
        uint32_t v1 = S[t+1024] + ((t+1024+off) < 2048 ? S[t+1024+off] : 0);
        __syncthreads();
        S[t] = v0; S[t+1024] = v1;
        __syncthreads();
    }
    for (int k = 0; k < 2; ++k) {
        int bin = t + k*1024;
        uint32_t above = (bin < 2047) ? S[bin+1] : 0;
        if (S[bin] >= R1 && above < R1) shB2 = bin;
    }
    if (t == 0) ccnt = 0;
    __syncthreads();
    int B2 = shB2;
    uint32_t C2r = (B2 < 2047) ? S[B2+1] : 0;
    uint32_t R2 = R1 - C2r;                           // rank within sub-bin (>=1)
    uint64_t prefix = (((uint64_t)B1) << 11) | (uint64_t)B2;

    // ---------- pass 3: collect sub-bin keys, find exact K* ----------
    for (int j = t; j < N_PER; j += 1024) {
        uint64_t k64 = keyof(j);
        if ((k64 >> 42) == prefix) {
            uint32_t p = atomicAdd(&ccnt, 1u);
            if (p < 1024) coll[p] = k64;
        }
    }
    __syncthreads();
    int m = (int)min(ccnt, 1024u);
    for (int idx = t; idx < m; idx += 1024) {
        uint64_t k64 = coll[idx];
        uint32_t r = 0;
        for (int q = 0; q < m; ++q) r += (coll[q] > k64) ? 1u : 0u;
        if (r == R2 - 1) shKstar = k64;               // the 6000th-largest key
    }
    if (t == 0) gcnt = 0;
    __syncthreads();
    uint64_t Kstar = shKstar;

    // ---------- gather selected keys (key >= K*) into sortbuf ----------
    for (int s = t; s < 8192; s += 1024) sortbuf[s] = 0ull;   // pad sorts last
    __syncthreads();
    for (int j = t; j < N_PER; j += 1024) {
        uint64_t k64 = keyof(j);
        if (k64 >= Kstar) {
            uint32_t p = atomicAdd(&gcnt, 1u);
            sortbuf[p] = k64;                          // exactly PRE_NMS appended
        }
    }
    __syncthreads();

    // ---------- bitonic sort 8192 u64 descending, all in LDS ----------
    for (int size = 2; size <= 8192; size <<= 1) {
        for (int stride = size >> 1; stride > 0; stride >>= 1) {
            #pragma unroll
            for (int k = 0; k < 4; ++k) {
                int p = t + (k << 10);
                int idx = ((p & ~(stride-1)) << 1) | (p & (stride-1));
                int q = idx | stride;
                bool up = (idx & size) == 0;           // descending overall
                uint64_t x = sortbuf[idx], y = sortbuf[q];
                if (up ? (x < y) : (x > y)) { sortbuf[idx] = y; sortbuf[q] = x; }
            }
            __syncthreads();
        }
    }

    // ---------- decode boxes for the sorted top-6000 ----------
    float maxx = img_info[1] - 1.0f;
    float maxy = img_info[0] - 1.0f;
    for (int r = t; r < PRE_NMS; r += 1024) {
        uint64_t k64 = sortbuf[r];
        uint32_t i = ~(uint32_t)(k64 & 0xFFFFFFFFu);
        int a = (int)(i % 9u);
        int hw = (int)(i / 9u);
        int h = hw >> 6, w = hw & 63;
        float sx = (float)(w * FEAT_STRIDE);
        float sy = (float)(h * FEAT_STRIDE);
        float ax1 = anchors[a*4+0] + sx;
        float ay1 = anchors[a*4+1] + sy;
        float ax2 = anchors[a*4+2] + sx;
        float ay2 = anchors[a*4+3] + sy;
        float width  = ax2 - ax1 + 1.0f;
        float height = ay2 - ay1 + 1.0f;
        float cx = ax1 + 0.5f * width;
        float cy = ay1 + 0.5f * height;
        size_t base = ((size_t)b*36 + a*4) * 4096 + hw;
        float dx = deltas[base];
        float dy = deltas[base + 4096];
        float dw = deltas[base + 2*4096];
        float dh = deltas[base + 3*4096];
        float pcx = dx * width + cx;
        float pcy = dy * height + cy;
        float pw = (float)exp((double)dw) * width;     // correctly-rounded f32 exp
        float ph = (float)exp((double)dh) * height;
        float x1 = pcx - 0.5f * pw;
        float y1 = pcy - 0.5f * ph;
        float x2 = pcx + 0.5f * pw;
        float y2 = pcy + 0.5f * ph;
        x1 = fminf(fmaxf(x1, 0.0f), maxx);
        y1 = fminf(fmaxf(y1, 0.0f), maxy);
        x2 = fminf(fmaxf(x2, 0.0f), maxx);
        y2 = fminf(fmaxf(y2, 0.0f), maxy);
        *(float4*)(topb + ((size_t)b*PRE_NMS + r)*4) = make_float4(x1, y1, x2, y2);
    }
}

// =====================================================================
// Kernel 2: triangular suppression bitmask. Row i word jb holds, for
// ranks j in [64jb, 64jb+64), whether IoU(i,j) > 0.7. Only jb >= i/64
// blocks are computed; unwritten words carry poison that can only mark
// ranks < i (already decided by scan time) -> harmless.
// =====================================================================
__global__ void __launch_bounds__(64) nms_mask(const float* __restrict__ topb,
                                               uint64_t* __restrict__ mask) {
#pragma clang fp contract(off)
    int jblock = blockIdx.x;  // 0..93
    int iblock = blockIdx.y;  // 0..93
    if (jblock < iblock) return;
    int b = blockIdx.z;
    int t = threadIdx.x;      // 0..63
    __shared__ float4 jb[64];
    __shared__ float jarea[64];
    int j0 = jblock*64;
    int jcount = min(64, PRE_NMS - j0);
    if (t < jcount) {
        float4 bj = *(const float4*)(topb + ((size_t)b*PRE_NMS + j0 + t)*4);
        jb[t] = bj;
        jarea[t] = (bj.z - bj.x + 1.0f) * (bj.w - bj.y + 1.0f);
    }
    __syncthreads();
    int i = iblock*64 + t;
    if (i >= PRE_NMS) return;
    float4 bi = *(const float4*)(topb + ((size_t)b*PRE_NMS + i)*4);
    float areai = (bi.z - bi.x + 1.0f) * (bi.w - bi.y + 1.0f);
    uint64_t bits = 0;
    for (int jj = 0; jj < jcount; ++jj) {
        float4 bj = jb[jj];
        float xx1 = fmaxf(bi.x, bj.x);
        float yy1 = fmaxf(bi.y, bj.y);
        float xx2 = fminf(bi.z, bj.z);
        float yy2 = fminf(bi.w, bj.w);
        float iw = fmaxf(0.0f, xx2 - xx1 + 1.0f);
        float ih = fmaxf(0.0f, yy2 - yy1 + 1.0f);
        float inter = iw * ih;
        float iou = inter / ((areai + jarea[jj]) - inter);
        if (iou > NMS_THRESH) bits |= (1ull << jj);
    }
    mask[((size_t)b*PRE_NMS + i)*JWORDS + jblock] = bits;
}

// =====================================================================
// Kernel 3: single-wave greedy scan with 3-deep row prefetch.
// remv bitset in registers: lane l owns words 2l, 2l+1 (l < 47).
// After OR-ing row(cur), first-live IS the exact next keep; 2nd/3rd
// ahead are predictions (mispredict only if an intervening kept row
// suppresses that specific box -> rare). 3 rotating row buffers keep
// 3 loads in flight -> compiler emits counted vmcnt, hiding latency.
// =====================================================================
__global__ void __launch_bounds__(64) nms_scan_pf(const uint64_t* __restrict__ mask,
                                                  const float* __restrict__ topb,
                                                  float* __restrict__ out) {
    int b = blockIdx.x;
    int l = threadIdx.x;
    __shared__ int keepL[POST_NMS];
    const uint64_t* mbase = mask + (size_t)b*PRE_NMS*JWORDS;
    int off = (l < 47) ? l*16 : 0;   // byte offset of this lane's 16B row slice

    uint64_t r0, r1;
    if (l < 46)      { r0 = 0ull; r1 = 0ull; }
    else if (l == 46){ r0 = 0ull; r1 = ~((1ull << 48) - 1); } // ranks 6000..6015 dead
    else             { r0 = ~0ull; r1 = ~0ull; }              // lanes 47..63 own nothing

    auto rowptr = [&](int r) {
        return (const ulonglong2*)((const char*)(mbase + (size_t)r*JWORDS) + off);
    };
    auto firstlive = [&](uint64_t a0, uint64_t a1) -> int {
        int local = a0 ? (l*128 + __builtin_ctzll(a0))
                       : (a1 ? (l*128 + 64 + __builtin_ctzll(a1)) : 0x7FFFFFFF);
        uint64_t mb = __ballot((a0 | a1) != 0ull);
        if (mb == 0ull) return -1;
        int fl = __builtin_ctzll(mb);
        return __builtin_amdgcn_readlane(local, fl);
    };
    auto clearbit = [&](uint64_t& c0, uint64_t& c1, int n) {
        if (l == (n >> 7)) {
            if (n & 64) c1 &= ~(1ull << (n & 63));
            else        c0 &= ~(1ull << (n & 63));
        }
    };

    int cur = 0, nkeep = 0;
    int tag0 = 0, tag1 = 1, tag2 = 2;
    ulonglong2 v0 = *rowptr(0);
    ulonglong2 v1 = *rowptr(1);
    ulonglong2 v2 = *rowptr(2);

    auto step = [&](ulonglong2& V, int& TAG) -> bool {
        if (l == 0) keepL[nkeep] = cur;
        nkeep++;
        if (nkeep >= POST_NMS) return true;
        if (TAG != cur) {            // mispredict: fresh load (waits vmcnt(0) here only)
            ulonglong2 tmp = *rowptr(cur);
            r0 |= tmp.x; r1 |= tmp.y;
        } else {                     // hit: counted wait (load issued 3 steps ago)
            r0 |= V.x; r1 |= V.y;
        }
        if (l == (cur >> 7)) {       // explicit self-kill (belt and braces)
            if (cur & 64) r1 |= 1ull << (cur & 63);
            else          r0 |= 1ull << (cur & 63);
        }
        uint64_t lv0 = ~r0, lv1 = ~r1;
        int n1 = firstlive(lv0, lv1);          // EXACT next keep
        if (n1 < 0) return true;
        uint64_t c0 = lv0, c1 = lv1;
        clearbit(c0, c1, n1);
        int n2 = firstlive(c0, c1);
        int n3 = -1;
        if (n2 >= 0) { clearbit(c0, c1, n2); n3 = firstlive(c0, c1); }
        V = *rowptr((n3 >= 0) ? n3 : 0);       // prefetch 3 ahead
        TAG = (n3 >= 0) ? n3 : -1;
        cur = n1;
        return false;
    };

    for (;;) {
        if (step(v0, tag0)) break;
        if (step(v1, tag1)) break;
        if (step(v2, tag2)) break;
    }
    __syncthreads();

    for (int k = l; k < POST_NMS; k += 64) {
        float* o = out + ((size_t)b*POST_NMS + k)*5;
        o[0] = (float)b;
        if (k < nkeep) {
            float4 bx = *(const float4*)(topb + ((size_t)b*PRE_NMS + keepL[k])*4);
            o[1] = bx.x; o[2] = bx.y; o[3] = bx.z; o[4] = bx.w;
        } else {
            o[1] = 0.0f; o[2] = 0.0f; o[3] = 0.0f; o[4] = 0.0f;
        }
    }
}

extern "C" void kernel_launch(void* const* d_in, const int* in_sizes, int n_in,
                              void* d_out, int out_size, void* d_ws, size_t ws_size,
                              hipStream_t stream) {
    const float* scores   = (const float*)d_in[0];
    const float* deltas   = (const float*)d_in[1];
    const float* img_info = (const float*)d_in[2];
    const float* anchors  = (const float*)d_in[3];
    float* out = (float*)d_out;

    uint8_t* ws = (uint8_t*)d_ws;
    float*    topb = (float*)ws;                    //   384,000 B
    uint64_t* mask = (uint64_t*)(ws + 393216);      // 18,048,000 B (rows 752 B, 16B-aligned)

    select_sort<<<NB, 1024, 0, stream>>>(scores, deltas, img_info, anchors, topb);

    dim3 mg(JWORDS, JWORDS, NB);
    nms_mask<<<mg, 64, 0, stream>>>(topb, mask);

    nms_scan_pf<<<NB, 64, 0, stream>>>(mask, topb, out);
}